// Round 2
// baseline (758.416 us; speedup 1.0000x reference)
//
#include <hip/hip_runtime.h>
#include <hip/hip_bf16.h>

#define N_NODE 100000
#define N_REL  8
#define EMB    32
#define OUT    32
#define N_BASIS 30
#define E_EDGE 1600000
#define BATCH  16384
#define H1 64
#define H2 32
#define H3 16
#define NEG_SLOPE 0.2f

// ---------------------------------------------------------------- K0: w = weight @ basis
__global__ __launch_bounds__(256) void k0_basis(const float* __restrict__ weight,
                                                const float* __restrict__ basis,
                                                float* __restrict__ w) {
    int i = blockIdx.x * 256 + threadIdx.x;          // 8 * 1024 = 8192 outputs
    if (i >= N_REL * EMB * OUT) return;
    int r = i >> 10, fo = i & 1023;
    float acc = 0.f;
    #pragma unroll
    for (int b = 0; b < N_BASIS; b++)
        acc = fmaf(weight[r * N_BASIS + b], basis[b * (EMB * OUT) + fo], acc);
    w[i] = acc;
}

// ------------------- K1: p_i/p_j = (x@w[r]) . att halves, agg = x@root + bias (NO xh store)
__global__ __launch_bounds__(256) void k1_transform(const int* __restrict__ x_ids,
                                                    const float* __restrict__ emb,
                                                    const float* __restrict__ w,
                                                    const float* __restrict__ att,
                                                    const float* __restrict__ root,
                                                    const float* __restrict__ bias,
                                                    float* __restrict__ p_i,
                                                    float* __restrict__ p_j,
                                                    float* __restrict__ agg) {
    __shared__ float w_s[N_REL * EMB * OUT];   // 32 KB
    __shared__ float att_s[N_REL * 2 * OUT];   // 2 KB
    __shared__ float root_s[EMB * OUT];        // 4 KB
    __shared__ float bias_s[OUT];
    __shared__ float x_s[8 * EMB];             // 1 KB

    const int t = threadIdx.x;
    for (int i = t; i < N_REL * EMB * OUT; i += 256) w_s[i] = w[i];
    for (int i = t; i < N_REL * 2 * OUT; i += 256) att_s[i] = att[i];
    for (int i = t; i < EMB * OUT; i += 256) root_s[i] = root[i];
    if (t < OUT) bias_s[t] = bias[t];

    const int o = t & 31;          // output col
    const int r = t >> 5;          // relation
    __syncthreads();
    const float a_i = att_s[r * 2 * OUT + o];
    const float a_j = att_s[r * 2 * OUT + OUT + o];

    for (int n0 = blockIdx.x * 8; n0 < N_NODE; n0 += gridDim.x * 8) {
        int nload = min(8, N_NODE - n0);
        __syncthreads();
        if (t < nload * EMB) {
            int nn = t >> 5, f = t & 31;
            x_s[t] = emb[(long)x_ids[n0 + nn] * EMB + f];
        }
        __syncthreads();
        for (int u = 0; u < nload; u++) {
            int n = n0 + u;
            float acc = 0.f;
            #pragma unroll
            for (int f = 0; f < EMB; f++)
                acc = fmaf(x_s[u * EMB + f], w_s[(r * EMB + f) * OUT + o], acc);

            float pi = acc * a_i;
            float pj = acc * a_j;
            #pragma unroll
            for (int off = 16; off > 0; off >>= 1) {
                pi += __shfl_down(pi, off, 32);
                pj += __shfl_down(pj, off, 32);
            }
            if (o == 0) { p_i[n * N_REL + r] = pi; p_j[n * N_REL + r] = pj; }

            if (r == 0) {   // agg init = x@root + bias (one 32-lane group per node)
                float ra = bias_s[o];
                #pragma unroll
                for (int f = 0; f < EMB; f++)
                    ra = fmaf(x_s[u * EMB + f], root_s[f * OUT + o], ra);
                agg[(long)n * OUT + o] = ra;
            }
        }
    }
}

// ------------------------- K2: alpha = leaky(p_i+p_j); ex = exp(alpha); denom += ex
// (no max-subtraction: alpha is O(0.01) here, softmax is shift-invariant, exp is safe)
__global__ __launch_bounds__(256) void k2_alpha(const int* __restrict__ src,
                                                const int* __restrict__ dst,
                                                const int* __restrict__ et,
                                                const float* __restrict__ p_i,
                                                const float* __restrict__ p_j,
                                                float* __restrict__ ex,
                                                float* __restrict__ denom) {
    int e = blockIdx.x * 256 + threadIdx.x;
    if (e >= E_EDGE) return;
    int s = src[e], d = dst[e], r = et[e];
    float a = p_i[d * N_REL + r] + p_j[s * N_REL + r];
    a = (a >= 0.f) ? a : NEG_SLOPE * a;
    float v = __expf(a);
    ex[e] = v;
    atomicAdd(&denom[d * N_REL + r], v);
}

// ---------------- K4: agg[dst] += (ex/denom) * (x[src] @ w[et])  — xh recomputed on the fly
__global__ __launch_bounds__(256) void k4_scatter(const int* __restrict__ src,
                                                  const int* __restrict__ dst,
                                                  const int* __restrict__ et,
                                                  const int* __restrict__ x_ids,
                                                  const float* __restrict__ emb,
                                                  const float* __restrict__ ex,
                                                  const float* __restrict__ denom,
                                                  const float* __restrict__ w,
                                                  float* __restrict__ agg) {
    __shared__ float w_s[N_REL * EMB * OUT];   // 32 KB
    for (int i = threadIdx.x; i < N_REL * EMB * OUT; i += 256) w_s[i] = w[i];
    __syncthreads();
    const int o = threadIdx.x & 31;            // output col
    const int g = threadIdx.x >> 5;            // edge-group within block (0..7)
    for (int e = blockIdx.x * 8 + g; e < E_EDGE; e += gridDim.x * 8) {
        int s = src[e], d = dst[e], r = et[e];
        float al = ex[e] / (denom[d * N_REL + r] + 1e-16f);
        float x_o = emb[(long)x_ids[s] * EMB + o];     // coalesced 128B, L2-resident
        const float* wr = &w_s[r * EMB * OUT + o];
        float acc = 0.f;
        #pragma unroll
        for (int f = 0; f < EMB; f++)
            acc = fmaf(__shfl(x_o, f, 32), wr[f * OUT], acc);
        atomicAdd(&agg[(long)d * OUT + o], al * acc);
    }
}

// ---------------------------------------------------------------- K5: gather + MLP
__global__ __launch_bounds__(256) void k5_mlp(const int* __restrict__ users,
                                              const int* __restrict__ bundles,
                                              const float* __restrict__ agg,
                                              const float* __restrict__ W1,
                                              const float* __restrict__ b1,
                                              const float* __restrict__ W2,
                                              const float* __restrict__ b2,
                                              const float* __restrict__ W3,
                                              const float* __restrict__ b3,
                                              const float* __restrict__ Wo,
                                              const float* __restrict__ bo,
                                              float* __restrict__ out) {
    __shared__ float W1s[2 * OUT * H1], W2s[H1 * H2], W3s[H2 * H3], Wos[H3];
    __shared__ float b1s[H1], b2s[H2], b3s[H3];
    __shared__ float bos;
    int t = threadIdx.x;
    for (int i = t; i < 2 * OUT * H1; i += 256) W1s[i] = W1[i];
    for (int i = t; i < H1 * H2; i += 256) W2s[i] = W2[i];
    for (int i = t; i < H2 * H3; i += 256) W3s[i] = W3[i];
    if (t < H3) Wos[t] = Wo[t];
    if (t < H1) b1s[t] = b1[t];
    if (t < H2) b2s[t] = b2[t];
    if (t < H3) b3s[t] = b3[t];
    if (t == 0) bos = bo[0];
    __syncthreads();

    int wave = t >> 6;
    int l = t & 63;
    for (int b = blockIdx.x * 4 + wave; b < BATCH; b += gridDim.x * 4) {
        int u = users[b], v = bundles[b];
        float z = (l < 32) ? agg[(long)u * OUT + l] : agg[(long)v * OUT + (l - 32)];
        z = fmaxf(z, 0.f);                       // h = relu(agg) applied on gather

        float acc = b1s[l];
        for (int k = 0; k < 64; k++)
            acc = fmaf(__shfl(z, k, 64), W1s[k * H1 + l], acc);
        float h1 = fmaxf(acc, 0.f);

        int o2 = l & 31;
        acc = b2s[o2];
        for (int k = 0; k < 64; k++)
            acc = fmaf(__shfl(h1, k, 64), W2s[k * H2 + o2], acc);
        float h2 = fmaxf(acc, 0.f);

        int o3 = l & 15;
        acc = b3s[o3];
        for (int k = 0; k < 32; k++)
            acc = fmaf(__shfl(h2, k, 64), W3s[k * H3 + o3], acc);
        float h3 = fmaxf(acc, 0.f);

        float term = (l < 16) ? h3 * Wos[l] : 0.f;
        #pragma unroll
        for (int off = 8; off; off >>= 1) term += __shfl_down(term, off, 64);
        if (l == 0) out[b] = term + bos;
    }
}

extern "C" void kernel_launch(void* const* d_in, const int* in_sizes, int n_in,
                              void* d_out, int out_size, void* d_ws, size_t ws_size,
                              hipStream_t stream) {
    (void)in_sizes; (void)n_in; (void)out_size; (void)ws_size;
    const int*   x_ids  = (const int*)d_in[0];
    const int*   eidx   = (const int*)d_in[1];     // (2,E): row0=src, row1=dst
    const int*   etype  = (const int*)d_in[2];
    const int*   users  = (const int*)d_in[3];
    const int*   bund   = (const int*)d_in[4];
    const float* emb    = (const float*)d_in[5];
    const float* basis  = (const float*)d_in[6];
    const float* weight = (const float*)d_in[7];
    const float* att    = (const float*)d_in[8];
    const float* root   = (const float*)d_in[9];
    const float* bias   = (const float*)d_in[10];
    const float* W1 = (const float*)d_in[11]; const float* b1 = (const float*)d_in[12];
    const float* W2 = (const float*)d_in[13]; const float* b2 = (const float*)d_in[14];
    const float* W3 = (const float*)d_in[15]; const float* b3 = (const float*)d_in[16];
    const float* Wo = (const float*)d_in[17]; const float* bo = (const float*)d_in[18];
    float* out = (float*)d_out;

    const int* src = eidx;
    const int* dst = eidx + E_EDGE;

    // workspace layout (floats)
    float* ws     = (float*)d_ws;
    float* w      = ws;                                   //      8,192
    float* p_i    = w + N_REL * EMB * OUT;                //    800,000
    float* p_j    = p_i + N_NODE * N_REL;                 //    800,000
    float* agg    = p_j + N_NODE * N_REL;                 //  3,200,000
    float* ex     = agg + (long)N_NODE * OUT;             //  1,600,000
    float* denom  = ex + E_EDGE;                          //    800,000

    hipMemsetAsync(denom, 0, (size_t)(N_NODE * N_REL) * sizeof(float), stream);

    k0_basis<<<(N_REL * EMB * OUT + 255) / 256, 256, 0, stream>>>(weight, basis, w);
    k1_transform<<<1024, 256, 0, stream>>>(x_ids, emb, w, att, root, bias,
                                           p_i, p_j, agg);
    k2_alpha<<<(E_EDGE + 255) / 256, 256, 0, stream>>>(src, dst, etype, p_i, p_j,
                                                       ex, denom);
    k4_scatter<<<4096, 256, 0, stream>>>(src, dst, etype, x_ids, emb, ex, denom, w, agg);
    k5_mlp<<<512, 256, 0, stream>>>(users, bund, agg, W1, b1, W2, b2, W3, b3,
                                    Wo, bo, out);
}

// Round 3
// 693.415 us; speedup vs baseline: 1.0937x; 1.0937x over previous
//
#include <hip/hip_runtime.h>
#include <hip/hip_bf16.h>

#define N_NODE 100000
#define N_REL  8
#define EMB    32
#define OUT    32
#define N_BASIS 30
#define E_EDGE 1600000
#define BATCH  16384
#define H1 64
#define H2 32
#define H3 16
#define NEG_SLOPE 0.2f
#define NB_SCAN 98          // ceil(100000/1024)

// ---------------------------------------------------------------- K0: w = weight @ basis
__global__ __launch_bounds__(256) void k0_basis(const float* __restrict__ weight,
                                                const float* __restrict__ basis,
                                                float* __restrict__ w) {
    int i = blockIdx.x * 256 + threadIdx.x;
    if (i >= N_REL * EMB * OUT) return;
    int r = i >> 10, fo = i & 1023;
    float acc = 0.f;
    #pragma unroll
    for (int b = 0; b < N_BASIS; b++)
        acc = fmaf(weight[r * N_BASIS + b], basis[b * (EMB * OUT) + fo], acc);
    w[i] = acc;
}

// -------- K1: xh = x@w (materialized), p_i/p_j = xh . att halves, agg = x@root + bias
__global__ __launch_bounds__(256) void k1_transform(const int* __restrict__ x_ids,
                                                    const float* __restrict__ emb,
                                                    const float* __restrict__ w,
                                                    const float* __restrict__ att,
                                                    const float* __restrict__ root,
                                                    const float* __restrict__ bias,
                                                    float* __restrict__ xh,
                                                    float* __restrict__ p_i,
                                                    float* __restrict__ p_j,
                                                    float* __restrict__ agg) {
    __shared__ float w_s[N_REL * EMB * OUT];   // 32 KB
    __shared__ float att_s[N_REL * 2 * OUT];
    __shared__ float root_s[EMB * OUT];
    __shared__ float bias_s[OUT];
    __shared__ float x_s[4 * EMB];

    const int t = threadIdx.x;
    for (int i = t; i < N_REL * EMB * OUT; i += 256) w_s[i] = w[i];
    for (int i = t; i < N_REL * 2 * OUT; i += 256) att_s[i] = att[i];
    for (int i = t; i < EMB * OUT; i += 256) root_s[i] = root[i];
    if (t < OUT) bias_s[t] = bias[t];
    __syncthreads();

    const int o = t & 31;
    const int r = t >> 5;
    const float a_i = att_s[r * 2 * OUT + o];
    const float a_j = att_s[r * 2 * OUT + OUT + o];

    for (int n0 = blockIdx.x * 4; n0 < N_NODE; n0 += gridDim.x * 4) {
        int nload = min(4, N_NODE - n0);
        if (t < nload * EMB) {
            int nn = t >> 5, f = t & 31;
            x_s[t] = emb[(long)x_ids[n0 + nn] * EMB + f];
        }
        __syncthreads();
        for (int u = 0; u < nload; u++) {
            int n = n0 + u;
            float acc = 0.f;
            #pragma unroll
            for (int f = 0; f < EMB; f++)
                acc = fmaf(x_s[u * EMB + f], w_s[(r * EMB + f) * OUT + o], acc);
            xh[((long)n * N_REL + r) * OUT + o] = acc;   // row index = n*8+r

            float pi = acc * a_i;
            float pj = acc * a_j;
            #pragma unroll
            for (int off = 16; off > 0; off >>= 1) {
                pi += __shfl_down(pi, off, 32);
                pj += __shfl_down(pj, off, 32);
            }
            if (o == 0) { p_i[n * N_REL + r] = pi; p_j[n * N_REL + r] = pj; }

            if (r == 0) {
                float ra = bias_s[o];
                #pragma unroll
                for (int f = 0; f < EMB; f++)
                    ra = fmaf(x_s[u * EMB + f], root_s[f * OUT + o], ra);
                agg[(long)n * OUT + o] = ra;
            }
        }
        __syncthreads();
    }
}

// ---------------------------------------------------------------- histogram over dst
__global__ __launch_bounds__(256) void k_hist(const int* __restrict__ dst,
                                              unsigned* __restrict__ counts) {
    int e = blockIdx.x * 256 + threadIdx.x;
    if (e >= E_EDGE) return;
    atomicAdd(&counts[dst[e]], 1u);
}

// ---------------------------------------------------------------- scan (3 kernels)
__global__ __launch_bounds__(256) void k_scanA(const unsigned* __restrict__ counts,
                                               unsigned* __restrict__ scanned,
                                               unsigned* __restrict__ blocksum) {
    __shared__ unsigned tsum[256];
    int b0 = blockIdx.x * 1024;
    int t = threadIdx.x;
    unsigned v[4]; unsigned s = 0;
    #pragma unroll
    for (int k = 0; k < 4; k++) {
        int idx = b0 + t * 4 + k;
        v[k] = (idx < N_NODE) ? counts[idx] : 0u;
        s += v[k];
    }
    tsum[t] = s;
    __syncthreads();
    for (int off = 1; off < 256; off <<= 1) {
        unsigned y = (t >= off) ? tsum[t - off] : 0u;
        __syncthreads();
        tsum[t] += y;
        __syncthreads();
    }
    unsigned run = tsum[t] - s;       // exclusive offset of this thread's chunk
    #pragma unroll
    for (int k = 0; k < 4; k++) {
        int idx = b0 + t * 4 + k;
        if (idx < N_NODE) scanned[idx] = run;
        run += v[k];
    }
    if (t == 255) blocksum[blockIdx.x] = tsum[255];
}

__global__ __launch_bounds__(256) void k_scanB(unsigned* __restrict__ blocksum) {
    __shared__ unsigned s[256];
    int t = threadIdx.x;
    unsigned v = (t < NB_SCAN) ? blocksum[t] : 0u;
    s[t] = v;
    __syncthreads();
    for (int off = 1; off < 256; off <<= 1) {
        unsigned y = (t >= off) ? s[t - off] : 0u;
        __syncthreads();
        s[t] += y;
        __syncthreads();
    }
    if (t < NB_SCAN) blocksum[t] = s[t] - v;   // exclusive
}

__global__ __launch_bounds__(256) void k_scanC(const unsigned* __restrict__ scanned,
                                               const unsigned* __restrict__ blocksum,
                                               int* __restrict__ base,
                                               unsigned* __restrict__ cursor) {
    int b0 = blockIdx.x * 1024;
    unsigned off = blocksum[blockIdx.x];
    #pragma unroll
    for (int k = 0; k < 4; k++) {
        int idx = b0 + threadIdx.x * 4 + k;
        if (idx < N_NODE) {
            unsigned b = scanned[idx] + off;
            base[idx] = (int)b;
            cursor[idx] = b;
        }
    }
    if (blockIdx.x == 0 && threadIdx.x == 0) base[N_NODE] = E_EDGE;
}

// ---------------------------------------------------------------- scatter into dst-sorted order
__global__ __launch_bounds__(256) void k_scatter(const int* __restrict__ src,
                                                 const int* __restrict__ dst,
                                                 const int* __restrict__ et,
                                                 unsigned* __restrict__ cursor,
                                                 int* __restrict__ payload) {
    int e = blockIdx.x * 256 + threadIdx.x;
    if (e >= E_EDGE) return;
    int d = dst[e];
    unsigned pos = atomicAdd(&cursor[d], 1u);
    payload[pos] = (src[e] << 3) | et[e];      // == xh row index == p_j index
}

// ------------- k_agg: one wave per dst. Two passes over its edges: denom per r, then weight.
__global__ __launch_bounds__(256) void k_agg(const int* __restrict__ base,
                                             const int* __restrict__ payload,
                                             const float* __restrict__ p_i,
                                             const float* __restrict__ p_j,
                                             const float* __restrict__ xh,
                                             float* __restrict__ agg) {
    int d = blockIdx.x * 4 + (threadIdx.x >> 6);
    if (d >= N_NODE) return;
    int lane = threadIdx.x & 63;
    int h = lane >> 5;          // half-wave: edge parity
    int o = lane & 31;          // output component
    int beg = base[d], end = base[d + 1];

    // pass 1: per-relation softmax denominators (registers, predicated adds)
    float sex[8] = {0.f,0.f,0.f,0.f,0.f,0.f,0.f,0.f};
    for (int i = beg + h; i < end; i += 2) {
        int sr = payload[i];
        int r = sr & 7;
        float a = p_i[(d << 3) | r] + p_j[sr];
        a = (a >= 0.f) ? a : NEG_SLOPE * a;
        float ev = __expf(a);
        #pragma unroll
        for (int k = 0; k < 8; k++) sex[k] += (r == k) ? ev : 0.f;
    }
    #pragma unroll
    for (int k = 0; k < 8; k++) sex[k] += __shfl_xor(sex[k], 32, 64);

    // pass 2: alpha-weighted xh accumulate
    float v = 0.f;
    for (int i = beg + h; i < end; i += 2) {
        int sr = payload[i];
        int r = sr & 7;
        float a = p_i[(d << 3) | r] + p_j[sr];
        a = (a >= 0.f) ? a : NEG_SLOPE * a;
        float ev = __expf(a);
        float de = sex[0];
        #pragma unroll
        for (int k = 1; k < 8; k++) de = (r == k) ? sex[k] : de;
        float al = ev / (de + 1e-16f);
        float xv = xh[((long)sr << 5) + o];    // coalesced 128B row gather
        v = fmaf(al, xv, v);
    }
    v += __shfl_xor(v, 32, 64);
    if (h == 0) agg[(long)d * OUT + o] += v;   // wave owns d: plain RMW, no atomics
}

// ---------------------------------------------------------------- K5: gather + MLP
__global__ __launch_bounds__(256) void k5_mlp(const int* __restrict__ users,
                                              const int* __restrict__ bundles,
                                              const float* __restrict__ agg,
                                              const float* __restrict__ W1,
                                              const float* __restrict__ b1,
                                              const float* __restrict__ W2,
                                              const float* __restrict__ b2,
                                              const float* __restrict__ W3,
                                              const float* __restrict__ b3,
                                              const float* __restrict__ Wo,
                                              const float* __restrict__ bo,
                                              float* __restrict__ out) {
    __shared__ float W1s[2 * OUT * H1], W2s[H1 * H2], W3s[H2 * H3], Wos[H3];
    __shared__ float b1s[H1], b2s[H2], b3s[H3];
    __shared__ float bos;
    int t = threadIdx.x;
    for (int i = t; i < 2 * OUT * H1; i += 256) W1s[i] = W1[i];
    for (int i = t; i < H1 * H2; i += 256) W2s[i] = W2[i];
    for (int i = t; i < H2 * H3; i += 256) W3s[i] = W3[i];
    if (t < H3) Wos[t] = Wo[t];
    if (t < H1) b1s[t] = b1[t];
    if (t < H2) b2s[t] = b2[t];
    if (t < H3) b3s[t] = b3[t];
    if (t == 0) bos = bo[0];
    __syncthreads();

    int wave = t >> 6;
    int l = t & 63;
    for (int b = blockIdx.x * 4 + wave; b < BATCH; b += gridDim.x * 4) {
        int u = users[b], v = bundles[b];
        float z = (l < 32) ? agg[(long)u * OUT + l] : agg[(long)v * OUT + (l - 32)];
        z = fmaxf(z, 0.f);

        float acc = b1s[l];
        for (int k = 0; k < 64; k++)
            acc = fmaf(__shfl(z, k, 64), W1s[k * H1 + l], acc);
        float h1 = fmaxf(acc, 0.f);

        int o2 = l & 31;
        acc = b2s[o2];
        for (int k = 0; k < 64; k++)
            acc = fmaf(__shfl(h1, k, 64), W2s[k * H2 + o2], acc);
        float h2 = fmaxf(acc, 0.f);

        int o3 = l & 15;
        acc = b3s[o3];
        for (int k = 0; k < 32; k++)
            acc = fmaf(__shfl(h2, k, 64), W3s[k * H3 + o3], acc);
        float h3 = fmaxf(acc, 0.f);

        float term = (l < 16) ? h3 * Wos[l] : 0.f;
        #pragma unroll
        for (int off = 8; off; off >>= 1) term += __shfl_down(term, off, 64);
        if (l == 0) out[b] = term + bos;
    }
}

extern "C" void kernel_launch(void* const* d_in, const int* in_sizes, int n_in,
                              void* d_out, int out_size, void* d_ws, size_t ws_size,
                              hipStream_t stream) {
    (void)in_sizes; (void)n_in; (void)out_size; (void)ws_size;
    const int*   x_ids  = (const int*)d_in[0];
    const int*   eidx   = (const int*)d_in[1];     // (2,E): row0=src, row1=dst
    const int*   etype  = (const int*)d_in[2];
    const int*   users  = (const int*)d_in[3];
    const int*   bund   = (const int*)d_in[4];
    const float* emb    = (const float*)d_in[5];
    const float* basis  = (const float*)d_in[6];
    const float* weight = (const float*)d_in[7];
    const float* att    = (const float*)d_in[8];
    const float* root   = (const float*)d_in[9];
    const float* bias   = (const float*)d_in[10];
    const float* W1 = (const float*)d_in[11]; const float* b1 = (const float*)d_in[12];
    const float* W2 = (const float*)d_in[13]; const float* b2 = (const float*)d_in[14];
    const float* W3 = (const float*)d_in[15]; const float* b3 = (const float*)d_in[16];
    const float* Wo = (const float*)d_in[17]; const float* bo = (const float*)d_in[18];
    float* out = (float*)d_out;

    const int* src = eidx;
    const int* dst = eidx + E_EDGE;

    // workspace layout (4-byte elements)
    float* ws       = (float*)d_ws;
    float* w        = ws;                                  //      8,192
    float* xh       = w + N_REL * EMB * OUT;               // 25,600,000
    float* p_i      = xh + (long)N_NODE * N_REL * OUT;     //    800,000
    float* p_j      = p_i + N_NODE * N_REL;                //    800,000
    float* agg      = p_j + N_NODE * N_REL;                //  3,200,000
    unsigned* counts  = (unsigned*)(agg + (long)N_NODE * OUT); //   100,000
    unsigned* scanned = counts + N_NODE;                   //    100,000
    unsigned* blocksum= scanned + N_NODE;                  //        256
    int*      basep   = (int*)(blocksum + 256);            //    100,001
    unsigned* cursor  = (unsigned*)(basep + N_NODE + 1);   //    100,000
    int*      payload = (int*)(cursor + N_NODE);           //  1,600,000

    hipMemsetAsync(counts, 0, (size_t)N_NODE * sizeof(unsigned), stream);

    k0_basis<<<(N_REL * EMB * OUT + 255) / 256, 256, 0, stream>>>(weight, basis, w);
    k1_transform<<<2048, 256, 0, stream>>>(x_ids, emb, w, att, root, bias,
                                           xh, p_i, p_j, agg);
    k_hist<<<(E_EDGE + 255) / 256, 256, 0, stream>>>(dst, counts);
    k_scanA<<<NB_SCAN, 256, 0, stream>>>(counts, scanned, blocksum);
    k_scanB<<<1, 256, 0, stream>>>(blocksum);
    k_scanC<<<NB_SCAN, 256, 0, stream>>>(scanned, blocksum, basep, cursor);
    k_scatter<<<(E_EDGE + 255) / 256, 256, 0, stream>>>(src, dst, etype, cursor, payload);
    k_agg<<<(N_NODE + 3) / 4, 256, 0, stream>>>(basep, payload, p_i, p_j, xh, agg);
    k5_mlp<<<512, 256, 0, stream>>>(users, bund, agg, W1, b1, W2, b2, W3, b3,
                                    Wo, bo, out);
}

// Round 4
// 548.257 us; speedup vs baseline: 1.3833x; 1.2648x over previous
//
#include <hip/hip_runtime.h>
#include <hip/hip_bf16.h>

#define N_NODE 100000
#define N_REL  8
#define EMB    32
#define OUT    32
#define N_BASIS 30
#define E_EDGE 1600000
#define BATCH  16384
#define H1 64
#define H2 32
#define H3 16
#define NEG_SLOPE 0.2f
#define NB_SCAN 98          // ceil(100000/1024)

// ---------------------------------------------------------------- K0: w = weight @ basis
__global__ __launch_bounds__(256) void k0_basis(const float* __restrict__ weight,
                                                const float* __restrict__ basis,
                                                float* __restrict__ w) {
    int i = blockIdx.x * 256 + threadIdx.x;
    if (i >= N_REL * EMB * OUT) return;
    int r = i >> 10, fo = i & 1023;
    float acc = 0.f;
    #pragma unroll
    for (int b = 0; b < N_BASIS; b++)
        acc = fmaf(weight[r * N_BASIS + b], basis[b * (EMB * OUT) + fo], acc);
    w[i] = acc;
}

// -------- K1: xh = x@w (w-cols in VGPRs, x via scalar loads), p_i/p_j, agg-init, + dst hist
__global__ __launch_bounds__(256) void k1_transform(const int* __restrict__ x_ids,
                                                    const float* __restrict__ emb,
                                                    const float* __restrict__ w,
                                                    const float* __restrict__ att,
                                                    const float* __restrict__ root,
                                                    const float* __restrict__ bias,
                                                    const int* __restrict__ dst,
                                                    float* __restrict__ xh,
                                                    float* __restrict__ p_i,
                                                    float* __restrict__ p_j,
                                                    float* __restrict__ agg,
                                                    unsigned* __restrict__ counts) {
    const int t = threadIdx.x;
    const int o = t & 31;          // output col
    const int r = t >> 5;          // relation

    // hoist this thread's fixed weight column into VGPRs (once per block)
    float wc[EMB];
    #pragma unroll
    for (int f = 0; f < EMB; f++) wc[f] = w[(r * EMB + f) * OUT + o];
    float rc[EMB];
    #pragma unroll
    for (int f = 0; f < EMB; f++) rc[f] = root[f * OUT + o];   // used by r==0 only
    const float a_i = att[r * 2 * OUT + o];
    const float a_j = att[r * 2 * OUT + OUT + o];
    const float bs = bias[o];

    for (int n = blockIdx.x; n < N_NODE; n += gridDim.x) {
        int id = __builtin_amdgcn_readfirstlane(x_ids[n]);   // wave-uniform -> s_load path
        const float* __restrict__ xr = emb + (size_t)id * EMB;
        float acc = 0.f;
        #pragma unroll
        for (int f = 0; f < EMB; f++) acc = fmaf(xr[f], wc[f], acc);
        xh[(size_t)n * 256 + t] = acc;                        // row n*8+r, col o (coalesced)

        float pi = acc * a_i;
        float pj = acc * a_j;
        #pragma unroll
        for (int m = 16; m > 0; m >>= 1) {
            pi += __shfl_xor(pi, m, 64);
            pj += __shfl_xor(pj, m, 64);
        }
        if (o == 0) { p_i[(n << 3) | r] = pi; p_j[(n << 3) | r] = pj; }

        if (r == 0) {
            float ra = bs;
            #pragma unroll
            for (int f = 0; f < EMB; f++) ra = fmaf(xr[f], rc[f], ra);
            agg[(size_t)n * OUT + o] = ra;
        }
    }

    // fused histogram over dst (grid-stride)
    int gsz = gridDim.x * 256;
    for (int e = blockIdx.x * 256 + t; e < E_EDGE; e += gsz)
        atomicAdd(&counts[dst[e]], 1u);
}

// ---------------------------------------------------------------- scan A: per-block scan
__global__ __launch_bounds__(256) void k_scanA(const unsigned* __restrict__ counts,
                                               unsigned* __restrict__ scanned,
                                               unsigned* __restrict__ blocksum) {
    __shared__ unsigned tsum[256];
    int b0 = blockIdx.x * 1024;
    int t = threadIdx.x;
    unsigned v[4]; unsigned s = 0;
    #pragma unroll
    for (int k = 0; k < 4; k++) {
        int idx = b0 + t * 4 + k;
        v[k] = (idx < N_NODE) ? counts[idx] : 0u;
        s += v[k];
    }
    tsum[t] = s;
    __syncthreads();
    for (int off = 1; off < 256; off <<= 1) {
        unsigned y = (t >= off) ? tsum[t - off] : 0u;
        __syncthreads();
        tsum[t] += y;
        __syncthreads();
    }
    unsigned run = tsum[t] - s;
    #pragma unroll
    for (int k = 0; k < 4; k++) {
        int idx = b0 + t * 4 + k;
        if (idx < N_NODE) scanned[idx] = run;
        run += v[k];
    }
    if (t == 255) blocksum[blockIdx.x] = tsum[255];
}

// ------------------------- scan C (merged with B): each block reduces its own block-prefix
__global__ __launch_bounds__(256) void k_scanC(const unsigned* __restrict__ scanned,
                                               const unsigned* __restrict__ blocksum,
                                               int* __restrict__ base,
                                               unsigned* __restrict__ cursor) {
    __shared__ unsigned wpart[4];
    int t = threadIdx.x;
    unsigned v = (t < NB_SCAN && t < (int)blockIdx.x) ? blocksum[t] : 0u;
    #pragma unroll
    for (int m = 1; m <= 32; m <<= 1) v += __shfl_xor(v, m, 64);
    if ((t & 63) == 0) wpart[t >> 6] = v;
    __syncthreads();
    unsigned off = wpart[0] + wpart[1] + wpart[2] + wpart[3];
    int b0 = blockIdx.x * 1024;
    #pragma unroll
    for (int k = 0; k < 4; k++) {
        int idx = b0 + t * 4 + k;
        if (idx < N_NODE) {
            unsigned b = scanned[idx] + off;
            base[idx] = (int)b;
            cursor[idx] = b;
        }
    }
    if (blockIdx.x == 0 && t == 0) base[N_NODE] = E_EDGE;
}

// ---------------------------------------------------------------- scatter into dst-sorted order
__global__ __launch_bounds__(256) void k_scatter(const int* __restrict__ src,
                                                 const int* __restrict__ dst,
                                                 const int* __restrict__ et,
                                                 unsigned* __restrict__ cursor,
                                                 int* __restrict__ payload) {
    int e = blockIdx.x * 256 + threadIdx.x;
    if (e >= E_EDGE) return;
    int d = dst[e];
    unsigned pos = atomicAdd(&cursor[d], 1u);
    payload[pos] = (src[e] << 3) | et[e];      // == xh row index == p_j index
}

// ------------- k_agg: wave per dst. Pass 1 edge-parallel denom; pass 2 broadcast-gather.
__global__ __launch_bounds__(256) void k_agg(const int* __restrict__ base,
                                             const int* __restrict__ payload,
                                             const float* __restrict__ p_i,
                                             const float* __restrict__ p_j,
                                             const float* __restrict__ xh,
                                             float* __restrict__ agg) {
    int d = blockIdx.x * 4 + (threadIdx.x >> 6);
    if (d >= N_NODE) return;
    const int lane = threadIdx.x & 63;
    const int h = lane >> 5;          // half-wave id
    const int o = lane & 31;          // output component
    const int beg = base[d], end = base[d + 1];
    if (beg == end) return;           // agg keeps its init value

    // pass 1: per-relation softmax denominators, one lane per edge
    float sex[8] = {0.f,0.f,0.f,0.f,0.f,0.f,0.f,0.f};
    for (int i = beg + lane; i < end; i += 64) {
        int sr = payload[i];
        int r = sr & 7;
        float a = p_i[(d << 3) | r] + p_j[sr];
        a = (a >= 0.f) ? a : NEG_SLOPE * a;
        float ev = __expf(a);
        #pragma unroll
        for (int k = 0; k < 8; k++) sex[k] += (r == k) ? ev : 0.f;
    }
    #pragma unroll
    for (int k = 0; k < 8; k++) {
        #pragma unroll
        for (int m = 1; m <= 32; m <<= 1) sex[k] += __shfl_xor(sex[k], m, 64);
    }

    // pass 2: chunk of 64 edges: compute al edge-parallel, then pair-broadcast + gather
    float v0 = 0.f, v1 = 0.f;
    for (int c = beg; c < end; c += 64) {
        int i = c + lane;
        int sr = 0; float al = 0.f;
        if (i < end) {
            sr = payload[i];
            int r = sr & 7;
            float a = p_i[(d << 3) | r] + p_j[sr];
            a = (a >= 0.f) ? a : NEG_SLOPE * a;
            float ev = __expf(a);
            float de = sex[0];
            #pragma unroll
            for (int k = 1; k < 8; k++) de = (r == k) ? sex[k] : de;
            al = ev / (de + 1e-16f);
        }
        int m = min(64, end - c);
        int j0 = 0;
        for (; j0 + 4 <= m; j0 += 4) {
            int e0 = j0 + h, e1 = j0 + 2 + h;
            float a0 = __shfl(al, e0, 64); int s0 = __shfl(sr, e0, 64);
            float a1 = __shfl(al, e1, 64); int s1 = __shfl(sr, e1, 64);
            v0 = fmaf(a0, xh[((size_t)s0 << 5) + o], v0);
            v1 = fmaf(a1, xh[((size_t)s1 << 5) + o], v1);
        }
        if (j0 < m) {       // tail: out-of-range lanes carry al=0, contribute 0
            int e0 = j0 + h;
            float a0 = __shfl(al, e0, 64); int s0 = __shfl(sr, e0, 64);
            v0 = fmaf(a0, xh[((size_t)s0 << 5) + o], v0);
            if (j0 + 2 < m) {
                int e1 = j0 + 2 + h;
                float a1 = __shfl(al, e1, 64); int s1 = __shfl(sr, e1, 64);
                v1 = fmaf(a1, xh[((size_t)s1 << 5) + o], v1);
            }
        }
    }
    float v = v0 + v1;
    v += __shfl_xor(v, 32, 64);
    if (h == 0) agg[(size_t)d * OUT + o] += v;   // wave owns d: plain RMW
}

// ---------------------------------------------------------------- K5: gather + MLP
__global__ __launch_bounds__(256) void k5_mlp(const int* __restrict__ users,
                                              const int* __restrict__ bundles,
                                              const float* __restrict__ agg,
                                              const float* __restrict__ W1,
                                              const float* __restrict__ b1,
                                              const float* __restrict__ W2,
                                              const float* __restrict__ b2,
                                              const float* __restrict__ W3,
                                              const float* __restrict__ b3,
                                              const float* __restrict__ Wo,
                                              const float* __restrict__ bo,
                                              float* __restrict__ out) {
    __shared__ float W1s[2 * OUT * H1], W2s[H1 * H2], W3s[H2 * H3], Wos[H3];
    __shared__ float b1s[H1], b2s[H2], b3s[H3];
    __shared__ float bos;
    int t = threadIdx.x;
    for (int i = t; i < 2 * OUT * H1; i += 256) W1s[i] = W1[i];
    for (int i = t; i < H1 * H2; i += 256) W2s[i] = W2[i];
    for (int i = t; i < H2 * H3; i += 256) W3s[i] = W3[i];
    if (t < H3) Wos[t] = Wo[t];
    if (t < H1) b1s[t] = b1[t];
    if (t < H2) b2s[t] = b2[t];
    if (t < H3) b3s[t] = b3[t];
    if (t == 0) bos = bo[0];
    __syncthreads();

    int wave = t >> 6;
    int l = t & 63;
    for (int b = blockIdx.x * 4 + wave; b < BATCH; b += gridDim.x * 4) {
        int u = users[b], v = bundles[b];
        float z = (l < 32) ? agg[(long)u * OUT + l] : agg[(long)v * OUT + (l - 32)];
        z = fmaxf(z, 0.f);

        float acc = b1s[l];
        for (int k = 0; k < 64; k++)
            acc = fmaf(__shfl(z, k, 64), W1s[k * H1 + l], acc);
        float h1 = fmaxf(acc, 0.f);

        int o2 = l & 31;
        acc = b2s[o2];
        for (int k = 0; k < 64; k++)
            acc = fmaf(__shfl(h1, k, 64), W2s[k * H2 + o2], acc);
        float h2 = fmaxf(acc, 0.f);

        int o3 = l & 15;
        acc = b3s[o3];
        for (int k = 0; k < 32; k++)
            acc = fmaf(__shfl(h2, k, 64), W3s[k * H3 + o3], acc);
        float h3 = fmaxf(acc, 0.f);

        float term = (l < 16) ? h3 * Wos[l] : 0.f;
        #pragma unroll
        for (int off = 8; off; off >>= 1) term += __shfl_down(term, off, 64);
        if (l == 0) out[b] = term + bos;
    }
}

extern "C" void kernel_launch(void* const* d_in, const int* in_sizes, int n_in,
                              void* d_out, int out_size, void* d_ws, size_t ws_size,
                              hipStream_t stream) {
    (void)in_sizes; (void)n_in; (void)out_size; (void)ws_size;
    const int*   x_ids  = (const int*)d_in[0];
    const int*   eidx   = (const int*)d_in[1];     // (2,E): row0=src, row1=dst
    const int*   etype  = (const int*)d_in[2];
    const int*   users  = (const int*)d_in[3];
    const int*   bund   = (const int*)d_in[4];
    const float* emb    = (const float*)d_in[5];
    const float* basis  = (const float*)d_in[6];
    const float* weight = (const float*)d_in[7];
    const float* att    = (const float*)d_in[8];
    const float* root   = (const float*)d_in[9];
    const float* bias   = (const float*)d_in[10];
    const float* W1 = (const float*)d_in[11]; const float* b1 = (const float*)d_in[12];
    const float* W2 = (const float*)d_in[13]; const float* b2 = (const float*)d_in[14];
    const float* W3 = (const float*)d_in[15]; const float* b3 = (const float*)d_in[16];
    const float* Wo = (const float*)d_in[17]; const float* bo = (const float*)d_in[18];
    float* out = (float*)d_out;

    const int* src = eidx;
    const int* dst = eidx + E_EDGE;

    // workspace layout (4-byte elements)
    float* ws       = (float*)d_ws;
    float* w        = ws;                                  //      8,192
    float* xh       = w + N_REL * EMB * OUT;               // 25,600,000
    float* p_i      = xh + (long)N_NODE * N_REL * OUT;     //    800,000
    float* p_j      = p_i + N_NODE * N_REL;                //    800,000
    float* agg      = p_j + N_NODE * N_REL;                //  3,200,000
    unsigned* counts  = (unsigned*)(agg + (long)N_NODE * OUT); //   100,000
    unsigned* scanned = counts + N_NODE;                   //    100,000
    unsigned* blocksum= scanned + N_NODE;                  //        256
    int*      basep   = (int*)(blocksum + 256);            //    100,001
    unsigned* cursor  = (unsigned*)(basep + N_NODE + 1);   //    100,000
    int*      payload = (int*)(cursor + N_NODE);           //  1,600,000

    hipMemsetAsync(counts, 0, (size_t)N_NODE * sizeof(unsigned), stream);

    k0_basis<<<(N_REL * EMB * OUT + 255) / 256, 256, 0, stream>>>(weight, basis, w);
    k1_transform<<<2048, 256, 0, stream>>>(x_ids, emb, w, att, root, bias, dst,
                                           xh, p_i, p_j, agg, counts);
    k_scanA<<<NB_SCAN, 256, 0, stream>>>(counts, scanned, blocksum);
    k_scanC<<<NB_SCAN, 256, 0, stream>>>(scanned, blocksum, basep, cursor);
    k_scatter<<<(E_EDGE + 255) / 256, 256, 0, stream>>>(src, dst, etype, cursor, payload);
    k_agg<<<(N_NODE + 3) / 4, 256, 0, stream>>>(basep, payload, p_i, p_j, xh, agg);
    k5_mlp<<<512, 256, 0, stream>>>(users, bund, agg, W1, b1, W2, b2, W3, b3,
                                    Wo, bo, out);
}

// Round 5
// 522.203 us; speedup vs baseline: 1.4523x; 1.0499x over previous
//
#include <hip/hip_runtime.h>
#include <hip/hip_bf16.h>

#define N_NODE 100000
#define N_REL  8
#define EMB    32
#define OUT    32
#define N_BASIS 30
#define E_EDGE 1600000
#define BATCH  16384
#define H1 64
#define H2 32
#define H3 16
#define NEG_SLOPE 0.2f
#define NB_SCAN 98          // ceil(100000/1024)

// ---------------------------------------------------------------- K0: w = weight @ basis
__global__ __launch_bounds__(256) void k0_basis(const float* __restrict__ weight,
                                                const float* __restrict__ basis,
                                                float* __restrict__ w) {
    int i = blockIdx.x * 256 + threadIdx.x;
    if (i >= N_REL * EMB * OUT) return;
    int r = i >> 10, fo = i & 1023;
    float acc = 0.f;
    #pragma unroll
    for (int b = 0; b < N_BASIS; b++)
        acc = fmaf(weight[r * N_BASIS + b], basis[b * (EMB * OUT) + fo], acc);
    w[i] = acc;
}

// -------- K1: xh = x@w with 4-node ILP, p_i/p_j, agg-init, + dst histogram
__global__ __launch_bounds__(256) void k1_transform(const int* __restrict__ x_ids,
                                                    const float* __restrict__ emb,
                                                    const float* __restrict__ w,
                                                    const float* __restrict__ att,
                                                    const float* __restrict__ root,
                                                    const float* __restrict__ bias,
                                                    const int* __restrict__ dst,
                                                    float* __restrict__ xh,
                                                    float* __restrict__ p_i,
                                                    float* __restrict__ p_j,
                                                    float* __restrict__ agg,
                                                    unsigned* __restrict__ counts) {
    const int t = threadIdx.x;
    const int o = t & 31;          // output col
    const int r = t >> 5;          // relation

    // fixed weight column for this (r,o) in VGPRs
    float wc[EMB];
    #pragma unroll
    for (int f = 0; f < EMB; f++) wc[f] = w[(r * EMB + f) * OUT + o];
    float rc[EMB];
    #pragma unroll
    for (int f = 0; f < EMB; f++) rc[f] = root[f * OUT + o];
    const float a_i = att[r * 2 * OUT + o];
    const float a_j = att[r * 2 * OUT + OUT + o];
    const float bs = bias[o];

    // N_NODE % 4 == 0: no tail
    for (int n0 = blockIdx.x * 4; n0 < N_NODE; n0 += gridDim.x * 4) {
        const float* __restrict__ x0 =
            emb + (size_t)__builtin_amdgcn_readfirstlane(x_ids[n0 + 0]) * EMB;
        const float* __restrict__ x1 =
            emb + (size_t)__builtin_amdgcn_readfirstlane(x_ids[n0 + 1]) * EMB;
        const float* __restrict__ x2 =
            emb + (size_t)__builtin_amdgcn_readfirstlane(x_ids[n0 + 2]) * EMB;
        const float* __restrict__ x3 =
            emb + (size_t)__builtin_amdgcn_readfirstlane(x_ids[n0 + 3]) * EMB;

        float a0 = 0.f, a1 = 0.f, a2 = 0.f, a3 = 0.f;
        #pragma unroll
        for (int f = 0; f < EMB; f++) {      // 4 independent FMA chains
            a0 = fmaf(x0[f], wc[f], a0);
            a1 = fmaf(x1[f], wc[f], a1);
            a2 = fmaf(x2[f], wc[f], a2);
            a3 = fmaf(x3[f], wc[f], a3);
        }
        xh[(size_t)(n0 + 0) * 256 + t] = a0;   // coalesced 1KB per node
        xh[(size_t)(n0 + 1) * 256 + t] = a1;
        xh[(size_t)(n0 + 2) * 256 + t] = a2;
        xh[(size_t)(n0 + 3) * 256 + t] = a3;

        float q[8] = { a0 * a_i, a0 * a_j, a1 * a_i, a1 * a_j,
                       a2 * a_i, a2 * a_j, a3 * a_i, a3 * a_j };
        #pragma unroll
        for (int k = 0; k < 8; k++) {
            #pragma unroll
            for (int m = 16; m > 0; m >>= 1) q[k] += __shfl_xor(q[k], m, 64);
        }
        if (o == 0) {
            p_i[((n0 + 0) << 3) | r] = q[0]; p_j[((n0 + 0) << 3) | r] = q[1];
            p_i[((n0 + 1) << 3) | r] = q[2]; p_j[((n0 + 1) << 3) | r] = q[3];
            p_i[((n0 + 2) << 3) | r] = q[4]; p_j[((n0 + 2) << 3) | r] = q[5];
            p_i[((n0 + 3) << 3) | r] = q[6]; p_j[((n0 + 3) << 3) | r] = q[7];
        }

        if (r == 0) {   // agg init = x@root + bias (32 lanes of wave 0)
            float r0 = bs, r1 = bs, r2 = bs, r3 = bs;
            #pragma unroll
            for (int f = 0; f < EMB; f++) {
                r0 = fmaf(x0[f], rc[f], r0);
                r1 = fmaf(x1[f], rc[f], r1);
                r2 = fmaf(x2[f], rc[f], r2);
                r3 = fmaf(x3[f], rc[f], r3);
            }
            agg[(size_t)(n0 + 0) * OUT + o] = r0;
            agg[(size_t)(n0 + 1) * OUT + o] = r1;
            agg[(size_t)(n0 + 2) * OUT + o] = r2;
            agg[(size_t)(n0 + 3) * OUT + o] = r3;
        }
    }

    // fused histogram over dst (grid-stride)
    int gsz = gridDim.x * 256;
    for (int e = blockIdx.x * 256 + t; e < E_EDGE; e += gsz)
        atomicAdd(&counts[dst[e]], 1u);
}

// ---------------------------------------------------------------- scan A: per-block scan
__global__ __launch_bounds__(256) void k_scanA(const unsigned* __restrict__ counts,
                                               unsigned* __restrict__ scanned,
                                               unsigned* __restrict__ blocksum) {
    __shared__ unsigned tsum[256];
    int b0 = blockIdx.x * 1024;
    int t = threadIdx.x;
    unsigned v[4]; unsigned s = 0;
    #pragma unroll
    for (int k = 0; k < 4; k++) {
        int idx = b0 + t * 4 + k;
        v[k] = (idx < N_NODE) ? counts[idx] : 0u;
        s += v[k];
    }
    tsum[t] = s;
    __syncthreads();
    for (int off = 1; off < 256; off <<= 1) {
        unsigned y = (t >= off) ? tsum[t - off] : 0u;
        __syncthreads();
        tsum[t] += y;
        __syncthreads();
    }
    unsigned run = tsum[t] - s;
    #pragma unroll
    for (int k = 0; k < 4; k++) {
        int idx = b0 + t * 4 + k;
        if (idx < N_NODE) scanned[idx] = run;
        run += v[k];
    }
    if (t == 255) blocksum[blockIdx.x] = tsum[255];
}

// ------------------------- scan C: each block reduces its own block-prefix
__global__ __launch_bounds__(256) void k_scanC(const unsigned* __restrict__ scanned,
                                               const unsigned* __restrict__ blocksum,
                                               int* __restrict__ base,
                                               unsigned* __restrict__ cursor) {
    __shared__ unsigned wpart[4];
    int t = threadIdx.x;
    unsigned v = (t < NB_SCAN && t < (int)blockIdx.x) ? blocksum[t] : 0u;
    #pragma unroll
    for (int m = 1; m <= 32; m <<= 1) v += __shfl_xor(v, m, 64);
    if ((t & 63) == 0) wpart[t >> 6] = v;
    __syncthreads();
    unsigned off = wpart[0] + wpart[1] + wpart[2] + wpart[3];
    int b0 = blockIdx.x * 1024;
    #pragma unroll
    for (int k = 0; k < 4; k++) {
        int idx = b0 + t * 4 + k;
        if (idx < N_NODE) {
            unsigned b = scanned[idx] + off;
            base[idx] = (int)b;
            cursor[idx] = b;
        }
    }
    if (blockIdx.x == 0 && t == 0) base[N_NODE] = E_EDGE;
}

// ---------------------------------------------------------------- scatter into dst-sorted order
__global__ __launch_bounds__(256) void k_scatter(const int* __restrict__ src,
                                                 const int* __restrict__ dst,
                                                 const int* __restrict__ et,
                                                 unsigned* __restrict__ cursor,
                                                 int* __restrict__ payload) {
    int e = blockIdx.x * 256 + threadIdx.x;
    if (e >= E_EDGE) return;
    int d = dst[e];
    unsigned pos = atomicAdd(&cursor[d], 1u);
    payload[pos] = (src[e] << 3) | et[e];      // == xh row index == p_j index
}

// ------------- k_agg: wave per dst. Fast path (cnt<=64): single exp, ev lane-resident.
__global__ __launch_bounds__(256) void k_agg(const int* __restrict__ base,
                                             const int* __restrict__ payload,
                                             const float* __restrict__ p_i,
                                             const float* __restrict__ p_j,
                                             const float* __restrict__ xh,
                                             float* __restrict__ agg) {
    int d = blockIdx.x * 4 + (threadIdx.x >> 6);
    if (d >= N_NODE) return;
    const int lane = threadIdx.x & 63;
    const int h = lane >> 5;          // half-wave id
    const int o = lane & 31;          // output component
    const int beg = base[d], end = base[d + 1];
    const int cnt = end - beg;
    if (cnt == 0) return;

    float pid[8];                     // d is wave-uniform -> scalar loads
    #pragma unroll
    for (int k = 0; k < 8; k++) pid[k] = p_i[(d << 3) | k];

    if (cnt <= 64) {
        // --- one lane per edge: compute ev once, keep resident ---
        int sr = 0, r = 0; float ev = 0.f;
        if (lane < cnt) {
            sr = payload[beg + lane];
            r = sr & 7;
            float pi = pid[0];
            #pragma unroll
            for (int k = 1; k < 8; k++) pi = (r == k) ? pid[k] : pi;
            float a = pi + p_j[sr];
            a = (a >= 0.f) ? a : NEG_SLOPE * a;
            ev = __expf(a);
        }
        // 8-bucket butterfly (inactive lanes carry ev=0)
        float sex[8];
        #pragma unroll
        for (int k = 0; k < 8; k++) sex[k] = (r == k) ? ev : 0.f;
        #pragma unroll
        for (int k = 0; k < 8; k++) {
            #pragma unroll
            for (int m = 1; m <= 32; m <<= 1) sex[k] += __shfl_xor(sex[k], m, 64);
        }
        float de = sex[0];
        #pragma unroll
        for (int k = 1; k < 8; k++) de = (r == k) ? sex[k] : de;
        float al = ev / (de + 1e-16f);          // inactive: 0/(x+eps)=0

        // --- gather phase: half-wave per edge, 4 chains ---
        float v0 = 0.f, v1 = 0.f, v2 = 0.f, v3 = 0.f;
        for (int j0 = 0; j0 < cnt; j0 += 8) {   // cnt<=64 -> lane idx max 63
            float b0 = __shfl(al, j0 + h,     64); int t0 = __shfl(sr, j0 + h,     64);
            float b1 = __shfl(al, j0 + 2 + h, 64); int t1 = __shfl(sr, j0 + 2 + h, 64);
            float b2 = __shfl(al, j0 + 4 + h, 64); int t2 = __shfl(sr, j0 + 4 + h, 64);
            float b3 = __shfl(al, j0 + 6 + h, 64); int t3 = __shfl(sr, j0 + 6 + h, 64);
            v0 = fmaf(b0, xh[((size_t)t0 << 5) + o], v0);
            v1 = fmaf(b1, xh[((size_t)t1 << 5) + o], v1);
            v2 = fmaf(b2, xh[((size_t)t2 << 5) + o], v2);
            v3 = fmaf(b3, xh[((size_t)t3 << 5) + o], v3);
        }
        float v = (v0 + v1) + (v2 + v3);
        v += __shfl_xor(v, 32, 64);
        if (h == 0) agg[(size_t)d * OUT + o] += v;
        return;
    }

    // --- generic fallback (cnt > 64): two-pass, recompute ev ---
    float sex[8] = {0.f,0.f,0.f,0.f,0.f,0.f,0.f,0.f};
    for (int i = beg + lane; i < end; i += 64) {
        int sr = payload[i];
        int r = sr & 7;
        float pi = pid[0];
        #pragma unroll
        for (int k = 1; k < 8; k++) pi = (r == k) ? pid[k] : pi;
        float a = pi + p_j[sr];
        a = (a >= 0.f) ? a : NEG_SLOPE * a;
        float ev = __expf(a);
        #pragma unroll
        for (int k = 0; k < 8; k++) sex[k] += (r == k) ? ev : 0.f;
    }
    #pragma unroll
    for (int k = 0; k < 8; k++) {
        #pragma unroll
        for (int m = 1; m <= 32; m <<= 1) sex[k] += __shfl_xor(sex[k], m, 64);
    }
    float v0 = 0.f, v1 = 0.f;
    for (int c = beg; c < end; c += 64) {
        int i = c + lane;
        int sr = 0; float al = 0.f;
        if (i < end) {
            sr = payload[i];
            int r = sr & 7;
            float pi = pid[0];
            #pragma unroll
            for (int k = 1; k < 8; k++) pi = (r == k) ? pid[k] : pi;
            float a = pi + p_j[sr];
            a = (a >= 0.f) ? a : NEG_SLOPE * a;
            float ev = __expf(a);
            float de = sex[0];
            #pragma unroll
            for (int k = 1; k < 8; k++) de = (r == k) ? sex[k] : de;
            al = ev / (de + 1e-16f);
        }
        int m = min(64, end - c);
        for (int j0 = 0; j0 < m; j0 += 2) {
            int e0 = j0 + h;
            float a0 = __shfl(al, e0, 64); int s0 = __shfl(sr, e0, 64);
            if (e0 < m) v0 = fmaf(a0, xh[((size_t)s0 << 5) + o], v0);
        }
    }
    float v = v0 + v1;
    v += __shfl_xor(v, 32, 64);
    if (h == 0) agg[(size_t)d * OUT + o] += v;
}

// ---------------------------------------------------------------- K5: gather + MLP
__global__ __launch_bounds__(256) void k5_mlp(const int* __restrict__ users,
                                              const int* __restrict__ bundles,
                                              const float* __restrict__ agg,
                                              const float* __restrict__ W1,
                                              const float* __restrict__ b1,
                                              const float* __restrict__ W2,
                                              const float* __restrict__ b2,
                                              const float* __restrict__ W3,
                                              const float* __restrict__ b3,
                                              const float* __restrict__ Wo,
                                              const float* __restrict__ bo,
                                              float* __restrict__ out) {
    __shared__ float W1s[2 * OUT * H1], W2s[H1 * H2], W3s[H2 * H3], Wos[H3];
    __shared__ float b1s[H1], b2s[H2], b3s[H3];
    __shared__ float bos;
    int t = threadIdx.x;
    for (int i = t; i < 2 * OUT * H1; i += 256) W1s[i] = W1[i];
    for (int i = t; i < H1 * H2; i += 256) W2s[i] = W2[i];
    for (int i = t; i < H2 * H3; i += 256) W3s[i] = W3[i];
    if (t < H3) Wos[t] = Wo[t];
    if (t < H1) b1s[t] = b1[t];
    if (t < H2) b2s[t] = b2[t];
    if (t < H3) b3s[t] = b3[t];
    if (t == 0) bos = bo[0];
    __syncthreads();

    int wave = t >> 6;
    int l = t & 63;
    for (int b = blockIdx.x * 4 + wave; b < BATCH; b += gridDim.x * 4) {
        int u = users[b], v = bundles[b];
        float z = (l < 32) ? agg[(long)u * OUT + l] : agg[(long)v * OUT + (l - 32)];
        z = fmaxf(z, 0.f);

        float acc = b1s[l];
        for (int k = 0; k < 64; k++)
            acc = fmaf(__shfl(z, k, 64), W1s[k * H1 + l], acc);
        float h1 = fmaxf(acc, 0.f);

        int o2 = l & 31;
        acc = b2s[o2];
        for (int k = 0; k < 64; k++)
            acc = fmaf(__shfl(h1, k, 64), W2s[k * H2 + o2], acc);
        float h2 = fmaxf(acc, 0.f);

        int o3 = l & 15;
        acc = b3s[o3];
        for (int k = 0; k < 32; k++)
            acc = fmaf(__shfl(h2, k, 64), W3s[k * H3 + o3], acc);
        float h3 = fmaxf(acc, 0.f);

        float term = (l < 16) ? h3 * Wos[l] : 0.f;
        #pragma unroll
        for (int off = 8; off; off >>= 1) term += __shfl_down(term, off, 64);
        if (l == 0) out[b] = term + bos;
    }
}

extern "C" void kernel_launch(void* const* d_in, const int* in_sizes, int n_in,
                              void* d_out, int out_size, void* d_ws, size_t ws_size,
                              hipStream_t stream) {
    (void)in_sizes; (void)n_in; (void)out_size; (void)ws_size;
    const int*   x_ids  = (const int*)d_in[0];
    const int*   eidx   = (const int*)d_in[1];     // (2,E): row0=src, row1=dst
    const int*   etype  = (const int*)d_in[2];
    const int*   users  = (const int*)d_in[3];
    const int*   bund   = (const int*)d_in[4];
    const float* emb    = (const float*)d_in[5];
    const float* basis  = (const float*)d_in[6];
    const float* weight = (const float*)d_in[7];
    const float* att    = (const float*)d_in[8];
    const float* root   = (const float*)d_in[9];
    const float* bias   = (const float*)d_in[10];
    const float* W1 = (const float*)d_in[11]; const float* b1 = (const float*)d_in[12];
    const float* W2 = (const float*)d_in[13]; const float* b2 = (const float*)d_in[14];
    const float* W3 = (const float*)d_in[15]; const float* b3 = (const float*)d_in[16];
    const float* Wo = (const float*)d_in[17]; const float* bo = (const float*)d_in[18];
    float* out = (float*)d_out;

    const int* src = eidx;
    const int* dst = eidx + E_EDGE;

    // workspace layout (4-byte elements)
    float* ws       = (float*)d_ws;
    float* w        = ws;                                  //      8,192
    float* xh       = w + N_REL * EMB * OUT;               // 25,600,000
    float* p_i      = xh + (long)N_NODE * N_REL * OUT;     //    800,000
    float* p_j      = p_i + N_NODE * N_REL;                //    800,000
    float* agg      = p_j + N_NODE * N_REL;                //  3,200,000
    unsigned* counts  = (unsigned*)(agg + (long)N_NODE * OUT); //   100,000
    unsigned* scanned = counts + N_NODE;                   //    100,000
    unsigned* blocksum= scanned + N_NODE;                  //        256
    int*      basep   = (int*)(blocksum + 256);            //    100,001
    unsigned* cursor  = (unsigned*)(basep + N_NODE + 1);   //    100,000
    int*      payload = (int*)(cursor + N_NODE);           //  1,600,000

    hipMemsetAsync(counts, 0, (size_t)N_NODE * sizeof(unsigned), stream);

    k0_basis<<<(N_REL * EMB * OUT + 255) / 256, 256, 0, stream>>>(weight, basis, w);
    k1_transform<<<2048, 256, 0, stream>>>(x_ids, emb, w, att, root, bias, dst,
                                           xh, p_i, p_j, agg, counts);
    k_scanA<<<NB_SCAN, 256, 0, stream>>>(counts, scanned, blocksum);
    k_scanC<<<NB_SCAN, 256, 0, stream>>>(scanned, blocksum, basep, cursor);
    k_scatter<<<(E_EDGE + 255) / 256, 256, 0, stream>>>(src, dst, etype, cursor, payload);
    k_agg<<<(N_NODE + 3) / 4, 256, 0, stream>>>(basep, payload, p_i, p_j, xh, agg);
    k5_mlp<<<512, 256, 0, stream>>>(users, bund, agg, W1, b1, W2, b2, W3, b3,
                                    Wo, bo, out);
}